// Round 1
// baseline (583.221 us; speedup 1.0000x reference)
//
#include <hip/hip_runtime.h>

// Problem: x[B,S,V] -> out[B,S,V,D] = relu(LN_D(x*W[v]+b[v]) * gamma[v] + beta[v])
// B=16, S=2048, V=32, D=128. Output 537MB fp32 => write-BW bound.
//
// Closed-form LN stats (h_d = x*W_d + b_d is affine in x):
//   mu  = x*mean(W) + mean(b)
//   var = x^2*Var(W) + 2x*Cov(W,b) + Var(b)
//   out_d = relu( (x*(W_d-mW) + (b_d-mb)) * rsqrt(var+eps) * g_d + beta_d )
// Precompute A = (W-mW)*g, C = (b-mb)*g, and per-v poly (p2,p1,p0=Var(b)+eps).
// Hot kernel: out = relu(fma(fma(x,A,C), r, beta)), r = rsqrt(poly(x)).

#define EPS 1e-5f

constexpr int D = 128;
constexpr int V = 32;

__global__ __launch_bounds__(64) void precompute_kernel(
    const float* __restrict__ W,
    const float* __restrict__ Bv,
    const float* __restrict__ G,
    float* __restrict__ A,
    float* __restrict__ C,
    float* __restrict__ coef) {
  const int v = blockIdx.x;
  const int t = threadIdx.x;  // 64 threads; each handles d = t and t+64
  const float w0 = W[v * D + t],  w1 = W[v * D + t + 64];
  const float b0 = Bv[v * D + t], b1 = Bv[v * D + t + 64];

  float sw = w0 + w1, sb = b0 + b1;
  #pragma unroll
  for (int off = 32; off > 0; off >>= 1) {
    sw += __shfl_down(sw, off);
    sb += __shfl_down(sb, off);
  }
  const float mW = __shfl(sw, 0) * (1.0f / D);
  const float mB = __shfl(sb, 0) * (1.0f / D);

  const float cw0 = w0 - mW, cw1 = w1 - mW;
  const float cb0 = b0 - mB, cb1 = b1 - mB;

  float sww = cw0 * cw0 + cw1 * cw1;
  float swb = cw0 * cb0 + cw1 * cb1;
  float sbb = cb0 * cb0 + cb1 * cb1;
  #pragma unroll
  for (int off = 32; off > 0; off >>= 1) {
    sww += __shfl_down(sww, off);
    swb += __shfl_down(swb, off);
    sbb += __shfl_down(sbb, off);
  }
  if (t == 0) {
    coef[v * 4 + 0] = sww * (1.0f / D);          // p2
    coef[v * 4 + 1] = 2.0f * swb * (1.0f / D);   // p1
    coef[v * 4 + 2] = sbb * (1.0f / D) + EPS;    // p0
  }

  const float g0 = G[v * D + t], g1 = G[v * D + t + 64];
  A[v * D + t]      = cw0 * g0;
  A[v * D + t + 64] = cw1 * g1;
  C[v * D + t]      = cb0 * g0;
  C[v * D + t + 64] = cb1 * g1;
}

__global__ __launch_bounds__(256) void fused_kernel(
    const float* __restrict__ x,
    const float* __restrict__ A,
    const float* __restrict__ C,
    const float* __restrict__ beta,
    const float* __restrict__ coef,
    float* __restrict__ out,
    int n4) {
  const int stride = gridDim.x * blockDim.x;
  for (int i = blockIdx.x * blockDim.x + threadIdx.x; i < n4; i += stride) {
    const int d4  = i & 31;          // float4 index within D
    const int row = i >> 5;          // (b,s,v) flat row
    const int v   = row & (V - 1);

    const float xv = x[row];

    const int pidx = (v << 5) + d4;  // float4 index into [V, D/4] tables
    const float4 a4  = reinterpret_cast<const float4*>(A)[pidx];
    const float4 c4  = reinterpret_cast<const float4*>(C)[pidx];
    const float4 be4 = reinterpret_cast<const float4*>(beta)[pidx];

    const float p2 = coef[v * 4 + 0];
    const float p1 = coef[v * 4 + 1];
    const float p0 = coef[v * 4 + 2];
    const float r  = rsqrtf(fmaf(xv, fmaf(xv, p2, p1), p0));

    float4 o;
    o.x = fmaxf(fmaf(fmaf(xv, a4.x, c4.x), r, be4.x), 0.0f);
    o.y = fmaxf(fmaf(fmaf(xv, a4.y, c4.y), r, be4.y), 0.0f);
    o.z = fmaxf(fmaf(fmaf(xv, a4.z, c4.z), r, be4.z), 0.0f);
    o.w = fmaxf(fmaf(fmaf(xv, a4.w, c4.w), r, be4.w), 0.0f);

    reinterpret_cast<float4*>(out)[i] = o;
  }
}

extern "C" void kernel_launch(void* const* d_in, const int* in_sizes, int n_in,
                              void* d_out, int out_size, void* d_ws, size_t ws_size,
                              hipStream_t stream) {
  const float* x     = (const float*)d_in[0];
  const float* W     = (const float*)d_in[1];
  const float* b     = (const float*)d_in[2];
  const float* gamma = (const float*)d_in[3];
  const float* beta  = (const float*)d_in[4];
  float* out = (float*)d_out;

  // Workspace layout: A[V*D], C[V*D], coef[V*4]
  float* A    = (float*)d_ws;
  float* C    = A + V * D;
  float* coef = C + V * D;

  precompute_kernel<<<V, 64, 0, stream>>>(W, b, gamma, A, C, coef);

  const int n4 = out_size / 4;                 // 33,554,432 float4s
  const int threads = 256;
  const int blocks = 16384;                    // ~8 iters/thread grid-stride
  fused_kernel<<<blocks, threads, 0, stream>>>(x, A, C, beta, coef, out, n4);
}

// Round 3
// 520.599 us; speedup vs baseline: 1.1203x; 1.1203x over previous
//
#include <hip/hip_runtime.h>

// x[B,S,V] -> out[B,S,V,D] = relu(LN_D(x*W[v]+b[v]) * gamma[v] + beta[v])
// B=16,S=2048,V=32,D=128. Output 537MB fp32 => pure write-BW problem.
//
// Closed-form LN (h_d affine in x):
//   out_d = relu( (x*(W_d-mW) + (b_d-mb)) * gamma_d * rsqrt(x^2 p2 + x p1 + p0) + beta_d )
//   p2=Var(W), p1=2Cov(W,b), p0=Var(b)+eps.
//
// Structure: each thread owns a fixed (v, d4) -> params live in REGISTERS for
// the whole kernel (round 1 reloaded them from L1 every iteration, ~4x L1
// amplification over store traffic). Shuffle reduction computes the LN stats
// in-register (no precompute kernel, no workspace). Inner loop:
// 1 broadcast x load, ~15 VALU, 1 nontemporal float4 store (coalesced 4KB/block).

#define EPS 1e-5f

constexpr int D = 128;
constexpr int V = 32;
constexpr int BS_TOTAL = 16 * 2048;   // 32768 (b,s) rows
constexpr int NB = 512;               // blocks per v-group (4 groups -> 2048 blocks = 8/CU)
constexpr int CHUNK = BS_TOTAL / NB;  // 64 contiguous rows per block

typedef float vfloat4 __attribute__((ext_vector_type(4)));  // native vector, OK for nontemporal builtin

__global__ __launch_bounds__(256) void fused_kernel(
    const float* __restrict__ x,
    const float* __restrict__ W,
    const float* __restrict__ Bv,
    const float* __restrict__ G,
    const float* __restrict__ Beta,
    float* __restrict__ out) {
  const int t = threadIdx.x;
  const int d4 = t & 31;              // float4 column within D
  const int vl = t >> 5;              // 0..7 local variable index
  const int group = blockIdx.x & 3;   // which 8-variable group
  const int blk = blockIdx.x >> 2;    // 0..NB-1 row chunk
  const int v = group * 8 + vl;

  // ---- one-time param setup, all in registers ----
  const int pidx = v * (D / 4) + d4;
  const vfloat4 w4  = reinterpret_cast<const vfloat4*>(W)[pidx];
  const vfloat4 b4  = reinterpret_cast<const vfloat4*>(Bv)[pidx];
  const vfloat4 g4  = reinterpret_cast<const vfloat4*>(G)[pidx];
  const vfloat4 be4 = reinterpret_cast<const vfloat4*>(Beta)[pidx];

  // mean over D: reduce across the 32 lanes sharing v (xor masks <=16 stay
  // inside each 32-lane half of the wave64)
  float sw = w4.x + w4.y + w4.z + w4.w;
  float sb = b4.x + b4.y + b4.z + b4.w;
  #pragma unroll
  for (int off = 16; off > 0; off >>= 1) {
    sw += __shfl_xor(sw, off);
    sb += __shfl_xor(sb, off);
  }
  const float mW = sw * (1.0f / D);
  const float mB = sb * (1.0f / D);

  vfloat4 a4 = w4 - mW;   // centered (unscaled) W
  vfloat4 c4 = b4 - mB;   // centered (unscaled) b

  float sww = a4.x * a4.x + a4.y * a4.y + a4.z * a4.z + a4.w * a4.w;
  float swb = a4.x * c4.x + a4.y * c4.y + a4.z * c4.z + a4.w * c4.w;
  float sbb = c4.x * c4.x + c4.y * c4.y + c4.z * c4.z + c4.w * c4.w;
  #pragma unroll
  for (int off = 16; off > 0; off >>= 1) {
    sww += __shfl_xor(sww, off);
    swb += __shfl_xor(swb, off);
    sbb += __shfl_xor(sbb, off);
  }
  const float p2 = sww * (1.0f / D);
  const float p1 = 2.0f * swb * (1.0f / D);
  const float p0 = sbb * (1.0f / D) + EPS;

  // fold gamma into the affine terms
  a4 *= g4;
  c4 *= g4;

  // ---- streaming loop over 64 contiguous (b,s) rows ----
  const int bs0 = blk * CHUNK;
  vfloat4* op = reinterpret_cast<vfloat4*>(out);

  #pragma unroll 4
  for (int i = 0; i < CHUNK; ++i) {
    const int row = (bs0 + i) * V + v;           // (b,s,v) flat row
    const float xv = x[row];                     // broadcast across 32 lanes
    const float r = rsqrtf(fmaf(xv, fmaf(xv, p2, p1), p0));

    vfloat4 o;
    o.x = fmaxf(fmaf(fmaf(xv, a4.x, c4.x), r, be4.x), 0.0f);
    o.y = fmaxf(fmaf(fmaf(xv, a4.y, c4.y), r, be4.y), 0.0f);
    o.z = fmaxf(fmaf(fmaf(xv, a4.z, c4.z), r, be4.z), 0.0f);
    o.w = fmaxf(fmaf(fmaf(xv, a4.w, c4.w), r, be4.w), 0.0f);

    __builtin_nontemporal_store(o, op + row * (D / 4) + d4);
  }
}

extern "C" void kernel_launch(void* const* d_in, const int* in_sizes, int n_in,
                              void* d_out, int out_size, void* d_ws, size_t ws_size,
                              hipStream_t stream) {
  const float* x     = (const float*)d_in[0];
  const float* W     = (const float*)d_in[1];
  const float* b     = (const float*)d_in[2];
  const float* gamma = (const float*)d_in[3];
  const float* beta  = (const float*)d_in[4];
  float* out = (float*)d_out;

  fused_kernel<<<4 * NB, 256, 0, stream>>>(x, W, b, gamma, beta, out);
}